// Round 6
// baseline (935.908 us; speedup 1.0000x reference)
//
#include <hip/hip_runtime.h>

#define N_NODES 100000
#define DIM     128
#define RR      100
#define NE      400000
#define NBLK    196    // ceil(N_NODES / 512)
#define NPB     16     // dst nodes per fused block
#define SST     516    // Sacc row stride (floats): 2-way max LDS bank aliasing
#define XST     136    // Xs row stride (ushorts)

typedef float  floatx4 __attribute__((ext_vector_type(4)));
typedef __bf16 bf16x8  __attribute__((ext_vector_type(8)));

static __device__ __forceinline__ unsigned short f2b(float f) {
    union { float f; unsigned int i; } v; v.f = f;
    unsigned int u = v.i;
    unsigned int r = (u + 0x7fffu + ((u >> 16) & 1u)) >> 16;   // RNE
    return (unsigned short)r;
}
static __device__ __forceinline__ float b2f(unsigned int u16) {
    union { unsigned int i; float f; } v; v.i = u16 << 16; return v.f;
}

// ---- per-dst degree ------------------------------------------------------
__global__ void k_deg(const int* __restrict__ dst, int* __restrict__ deg, int E) {
    int e = blockIdx.x * 256 + threadIdx.x;
    if (e < E) atomicAdd(&deg[dst[e]], 1);
}

// ---- 2-level exclusive scan over deg[N] ----------------------------------
__global__ void k_scan_block(const int* __restrict__ deg, int* __restrict__ bsum) {
    __shared__ int sm[256];
    int b = blockIdx.x, t = threadIdx.x;
    int i0 = b * 512 + 2 * t;
    int a = (i0     < N_NODES) ? deg[i0]     : 0;
    int c = (i0 + 1 < N_NODES) ? deg[i0 + 1] : 0;
    sm[t] = a + c;
    __syncthreads();
    for (int s = 128; s > 0; s >>= 1) { if (t < s) sm[t] += sm[t + s]; __syncthreads(); }
    if (t == 0) bsum[b] = sm[0];
}

__global__ void k_scan_top(const int* __restrict__ bsum, int* __restrict__ boff) {
    __shared__ int sm[256];
    int t = threadIdx.x;
    int v = (t < NBLK) ? bsum[t] : 0;
    sm[t] = v;
    __syncthreads();
    for (int s = 1; s < 256; s <<= 1) {
        int u = (t >= s) ? sm[t - s] : 0;
        __syncthreads();
        sm[t] += u;
        __syncthreads();
    }
    if (t < NBLK) boff[t] = sm[t] - v;   // exclusive
}

__global__ void k_scan_down(const int* __restrict__ deg, const int* __restrict__ boff,
                            int* __restrict__ off) {
    __shared__ int sm[256];
    int b = blockIdx.x, t = threadIdx.x;
    int i0 = b * 512 + 2 * t;
    int a = (i0     < N_NODES) ? deg[i0]     : 0;
    int c = (i0 + 1 < N_NODES) ? deg[i0 + 1] : 0;
    int ts = a + c;
    sm[t] = ts;
    __syncthreads();
    for (int s = 1; s < 256; s <<= 1) {
        int u = (t >= s) ? sm[t - s] : 0;
        __syncthreads();
        sm[t] += u;
        __syncthreads();
    }
    int base = boff[b] + (sm[t] - ts);
    if (i0     < N_NODES) off[i0]     = base;
    if (i0 + 1 < N_NODES) off[i0 + 1] = base + a;
    if (b == 0 && t == 0) off[N_NODES] = NE;
}

// ---- scatter edges into dst-sorted CSR: desc = {src, et, dst, norm} ------
__global__ void k_scatter(const int* __restrict__ src, const int* __restrict__ dst,
                          const int* __restrict__ et, const int* __restrict__ off,
                          int* __restrict__ cursor, int4* __restrict__ edesc, int E) {
    int e = blockIdx.x * 256 + threadIdx.x;
    if (e >= E) return;
    int d = dst[e];
    int pos = off[d] + atomicAdd(&cursor[d], 1);
    edesc[pos] = make_int4(src[e], et[e], d, 0);
}

// ---- schlichtkrull norm: one thread per CSR slot, O(deg) scan ------------
__global__ void k_norm2(const int* __restrict__ off, int4* __restrict__ edesc, int E) {
    int p = blockIdx.x * 256 + threadIdx.x;
    if (p >= E) return;
    int4 me = edesc[p];
    int p0 = off[me.z], p1 = off[me.z + 1];
    int c = 0;
    for (int j = p0; j < p1; ++j)
        c += (((const int*)edesc)[4 * j + 1] == me.y) ? 1 : 0;
    ((int*)edesc)[4 * p + 3] = __float_as_int(1.0f / (float)c);
}

// ---- fused preprocessing: x0 | weight transpose | rel bf16 | penalty -----
__global__ void k_pre(const float* __restrict__ ent, const float* __restrict__ entb,
                      const float* __restrict__ bases1, const float* __restrict__ root1,
                      const float* __restrict__ bases2, const float* __restrict__ root2,
                      const float* __restrict__ rel,
                      unsigned short* __restrict__ x1,
                      unsigned short* __restrict__ wt1, unsigned short* __restrict__ wt2,
                      unsigned short* __restrict__ relb, float* __restrict__ out) {
    int b = blockIdx.x, t = threadIdx.x;
    if (b < 50000) {                                   // x0 = relu(ent + bias)
        int i = b * 256 + t;
        float v = ent[i] + entb[i & (DIM - 1)];
        x1[i] = f2b(v > 0.0f ? v : 0.0f);
    } else if (b < 50320) {                            // wt[m][k]: bases|root
        int i = (b - 50000) * 256 + t;                 // 128*640
        int m = i / 640, k = i - m * 640;
        float v1, v2;
        if (k < 512) {
            int bb = k >> 7, kin = k & 127;
            v1 = bases1[(bb * 128 + kin) * 128 + m];
            v2 = bases2[(bb * 128 + kin) * 128 + m];
        } else {
            int kin = k - 512;
            v1 = root1[kin * 128 + m];
            v2 = root2[kin * 128 + m];
        }
        wt1[i] = f2b(v1);
        wt2[i] = f2b(v2);
    } else if (b < 50370) {                            // rel -> bf16
        int i = (b - 50320) * 256 + t;                 // 12800
        relb[i] = f2b(rel[i]);
    } else {                                           // penalty
        __shared__ float sm[256];
        float v = 0.0f;
        for (int i = t; i < RR * DIM; i += 256) { float x = rel[i]; v += x * x; }
        sm[t] = v;
        __syncthreads();
        for (int s = 128; s > 0; s >>= 1) {
            if (t < s) sm[t] += sm[t + s];
            __syncthreads();
        }
        if (t == 0) out[NE] = sm[0];
    }
}

// ---- fused aggregate + GEMM, latency-tolerant ----------------------------
// Block = 256 thr (4 waves), 16 dst nodes. Phase A: waves take 16-edge CSR
// batches; 16 gathers prefetched per batch (independent); descriptors
// broadcast via readlane (SGPR); run-length-merged fp32 accumulation into
// LDS via ds_add_f32. Phase B: MFMA K=640 from fp32 LDS (v_perm bf16 pack)
// + X tile + WT direct (L2-resident).
__global__ __launch_bounds__(256) void k_fused(const unsigned short* __restrict__ X,
                                               const int4* __restrict__ edesc,
                                               const int* __restrict__ off,
                                               const float* __restrict__ comp,
                                               const unsigned short* __restrict__ WT,
                                               const float* __restrict__ bias,
                                               unsigned short* __restrict__ out,
                                               int do_relu) {
    __shared__ __align__(16) float Sacc[NPB * SST];            // 33 KB fp32 accum
    __shared__ __align__(16) unsigned short Xs[NPB * XST];     // 4.4 KB X tile
    __shared__ float4 Cs[RR];                                  // 1.6 KB comp

    const int t = threadIdx.x, wid = t >> 6, lane = t & 63;
    const int rbase = blockIdx.x * NPB;
    const int nrows = min(NPB, N_NODES - rbase);

    for (int i = t; i < NPB * SST; i += 256) Sacc[i] = 0.0f;
    if (t < RR) Cs[t] = ((const float4*)comp)[t];
    {   // stage full X tile: 16 rows x 16 chunks of 16B  (fix of r5 NaN bug)
        int row = t >> 4, ch = t & 15;
        uint4 v = make_uint4(0u, 0u, 0u, 0u);
        if (row < nrows) v = *(const uint4*)(X + (size_t)(rbase + row) * 128 + ch * 8);
        *(uint4*)(Xs + row * XST + ch * 8) = v;
    }
    __syncthreads();

    // ---------------- phase A: edge-parallel aggregation ----------------
    const int e0 = off[rbase], e1 = off[rbase + nrows];
    for (int base = e0 + wid * 16; base < e1; base += 64) {
        int cnt = min(16, e1 - base);
        int4 md = edesc[base + ((lane < cnt) ? lane : 0)];
        unsigned xp[16];
#pragma unroll
        for (int u = 0; u < 16; ++u) {                 // 16 independent gathers
            int jc = (u < cnt) ? u : 0;
            int s = (int)__builtin_amdgcn_readlane((unsigned)md.x, (unsigned)jc);
            xp[u] = *(const unsigned*)(X + (size_t)s * 128 + 2 * lane);
        }
        float r0 = 0, r1 = 0, r2 = 0, r3 = 0, r4 = 0, r5 = 0, r6 = 0, r7 = 0;
        int currow = -1;
#pragma unroll
        for (int u = 0; u < 16; ++u) {
            if (u < cnt) {                             // wave-uniform
                int row = (int)__builtin_amdgcn_readlane((unsigned)md.z, (unsigned)u) - rbase;
                int tt  = (int)__builtin_amdgcn_readlane((unsigned)md.y, (unsigned)u);
                float w = __int_as_float(__builtin_amdgcn_readlane((unsigned)md.w, (unsigned)u));
                if (row != currow) {                   // run boundary: flush
                    if (currow >= 0) {
                        float* rp = &Sacc[currow * SST + 2 * lane];
                        atomicAdd(rp + 0,   r0); atomicAdd(rp + 1,   r1);
                        atomicAdd(rp + 128, r2); atomicAdd(rp + 129, r3);
                        atomicAdd(rp + 256, r4); atomicAdd(rp + 257, r5);
                        atomicAdd(rp + 384, r6); atomicAdd(rp + 385, r7);
                    }
                    currow = row;
                    r0 = r1 = r2 = r3 = r4 = r5 = r6 = r7 = 0.0f;
                }
                float4 cc = Cs[tt];
                float x0 = b2f(xp[u] & 0xffffu), x1 = b2f(xp[u] >> 16);
                float w0 = w * cc.x, w1 = w * cc.y, w2 = w * cc.z, w3 = w * cc.w;
                r0 += w0 * x0; r1 += w0 * x1; r2 += w1 * x0; r3 += w1 * x1;
                r4 += w2 * x0; r5 += w2 * x1; r6 += w3 * x0; r7 += w3 * x1;
            }
        }
        if (currow >= 0) {
            float* rp = &Sacc[currow * SST + 2 * lane];
            atomicAdd(rp + 0,   r0); atomicAdd(rp + 1,   r1);
            atomicAdd(rp + 128, r2); atomicAdd(rp + 129, r3);
            atomicAdd(rp + 256, r4); atomicAdd(rp + 257, r5);
            atomicAdd(rp + 384, r6); atomicAdd(rp + 385, r7);
        }
    }
    __syncthreads();

    // ---------------- phase B: MFMA, m=16 n=128 K=640 ----------------
    const int quad = lane >> 4, lr = lane & 15;
    const int nb = wid * 32;
    floatx4 acc[2];
    acc[0] = (floatx4)0.0f; acc[1] = (floatx4)0.0f;

#pragma unroll
    for (int kc = 0; kc < 5; ++kc) {
#pragma unroll
        for (int ks = 0; ks < 4; ++ks) {
            bf16x8 a, b0, b1;
            if (kc < 4) {
                const uint4* p = (const uint4*)&Sacc[lr * SST + kc * 128 + ks * 32 + quad * 8];
                uint4 u0 = p[0], u1 = p[1];
                uint4 pk;
                pk.x = __builtin_amdgcn_perm(u0.y, u0.x, 0x07060302u);
                pk.y = __builtin_amdgcn_perm(u0.w, u0.z, 0x07060302u);
                pk.z = __builtin_amdgcn_perm(u1.y, u1.x, 0x07060302u);
                pk.w = __builtin_amdgcn_perm(u1.w, u1.z, 0x07060302u);
                a = *(bf16x8*)&pk;
            } else {
                a = *(const bf16x8*)(Xs + lr * XST + ks * 32 + quad * 8);
            }
            b0 = *(const bf16x8*)(WT + (size_t)(nb + lr) * 640      + kc * 128 + ks * 32 + quad * 8);
            b1 = *(const bf16x8*)(WT + (size_t)(nb + 16 + lr) * 640 + kc * 128 + ks * 32 + quad * 8);
            acc[0] = __builtin_amdgcn_mfma_f32_16x16x32_bf16(a, b0, acc[0], 0, 0, 0);
            acc[1] = __builtin_amdgcn_mfma_f32_16x16x32_bf16(a, b1, acc[1], 0, 0, 0);
        }
    }

    // C/D layout: col=lane&15, row=quad*4+reg  [m89/m91-verified]
#pragma unroll
    for (int reg = 0; reg < 4; ++reg) {
        int r = quad * 4 + reg;
        if (r >= nrows) continue;
        int grow = rbase + r;
#pragma unroll
        for (int nj = 0; nj < 2; ++nj) {
            int n = nb + nj * 16 + lr;
            float v = acc[nj][reg] + bias[n];
            if (do_relu) v = v > 0.0f ? v : 0.0f;
            out[(size_t)grow * 128 + n] = f2b(v);
        }
    }
}

// ---- DistMult score: 16 lanes per edge, bf16 gathers ---------------------
__global__ __launch_bounds__(256) void k_score(const unsigned short* __restrict__ xf,
                                               const int* __restrict__ src, const int* __restrict__ dst,
                                               const int* __restrict__ et,
                                               const unsigned short* __restrict__ relb,
                                               float* __restrict__ out, int E) {
    int g = threadIdx.x >> 4, li = threadIdx.x & 15;
    int e = blockIdx.x * 16 + g;
    if (e >= E) return;
    int s = src[e], d = dst[e], tt = et[e];
    uint4 au = *(const uint4*)(xf + (size_t)s * 128 + li * 8);
    uint4 bu = *(const uint4*)(xf + (size_t)d * 128 + li * 8);
    uint4 ru = *(const uint4*)(relb + (size_t)tt * 128 + li * 8);
    float v;
    v  = b2f(au.x & 0xffffu) * b2f(ru.x & 0xffffu) * b2f(bu.x & 0xffffu);
    v += b2f(au.x >> 16)     * b2f(ru.x >> 16)     * b2f(bu.x >> 16);
    v += b2f(au.y & 0xffffu) * b2f(ru.y & 0xffffu) * b2f(bu.y & 0xffffu);
    v += b2f(au.y >> 16)     * b2f(ru.y >> 16)     * b2f(bu.y >> 16);
    v += b2f(au.z & 0xffffu) * b2f(ru.z & 0xffffu) * b2f(bu.z & 0xffffu);
    v += b2f(au.z >> 16)     * b2f(ru.z >> 16)     * b2f(bu.z >> 16);
    v += b2f(au.w & 0xffffu) * b2f(ru.w & 0xffffu) * b2f(bu.w & 0xffffu);
    v += b2f(au.w >> 16)     * b2f(ru.w >> 16)     * b2f(bu.w >> 16);
    v += __shfl_xor(v, 8, 16);
    v += __shfl_xor(v, 4, 16);
    v += __shfl_xor(v, 2, 16);
    v += __shfl_xor(v, 1, 16);
    if (li == 0) out[e] = v;
}

extern "C" void kernel_launch(void* const* d_in, const int* in_sizes, int n_in,
                              void* d_out, int out_size, void* d_ws, size_t ws_size,
                              hipStream_t stream) {
    (void)in_sizes; (void)n_in; (void)out_size; (void)ws_size;
    const int* edge_index = (const int*)d_in[0];
    const int* edge_type  = (const int*)d_in[1];
    const float* ent    = (const float*)d_in[2];
    const float* entb   = (const float*)d_in[3];
    const float* bases1 = (const float*)d_in[4];
    const float* comp1  = (const float*)d_in[5];
    const float* root1  = (const float*)d_in[6];
    const float* bias1  = (const float*)d_in[7];
    const float* bases2 = (const float*)d_in[8];
    const float* comp2  = (const float*)d_in[9];
    const float* root2  = (const float*)d_in[10];
    const float* bias2  = (const float*)d_in[11];
    const float* rel    = (const float*)d_in[12];
    const int* src = edge_index;
    const int* dst = edge_index + NE;

    char* ws = (char*)d_ws;
    size_t off_b = 0;
    auto alloc = [&](size_t bytes) { void* p = ws + off_b; off_b = (off_b + bytes + 255) & ~(size_t)255; return p; };

    unsigned short* x1   = (unsigned short*)alloc((size_t)N_NODES * 128 * 2);  // 25.6 MB
    unsigned short* x2   = (unsigned short*)alloc((size_t)N_NODES * 128 * 2);  // 25.6 MB
    unsigned short* wt1  = (unsigned short*)alloc(128 * 640 * 2);
    unsigned short* wt2  = (unsigned short*)alloc(128 * 640 * 2);
    unsigned short* relb = (unsigned short*)alloc(RR * DIM * 2);
    int*   deg    = (int*)alloc((size_t)N_NODES * 4);
    int*   cursor = (int*)alloc((size_t)N_NODES * 4);
    int*   offv   = (int*)alloc((size_t)(N_NODES + 1) * 4);
    int*   bsum   = (int*)alloc(NBLK * 4);
    int*   boff   = (int*)alloc(NBLK * 4);
    int4*  edesc  = (int4*)alloc((size_t)NE * 16);                             // 6.4 MB

    float* out = (float*)d_out;

    hipMemsetAsync(deg, 0, (size_t)N_NODES * 4, stream);
    hipMemsetAsync(cursor, 0, (size_t)N_NODES * 4, stream);

    k_deg<<<(NE + 255) / 256, 256, 0, stream>>>(dst, deg, NE);
    k_scan_block<<<NBLK, 256, 0, stream>>>(deg, bsum);
    k_scan_top<<<1, 256, 0, stream>>>(bsum, boff);
    k_scan_down<<<NBLK, 256, 0, stream>>>(deg, boff, offv);
    k_scatter<<<(NE + 255) / 256, 256, 0, stream>>>(src, dst, edge_type, offv, cursor, edesc, NE);
    k_norm2<<<(NE + 255) / 256, 256, 0, stream>>>(offv, edesc, NE);
    k_pre<<<50371, 256, 0, stream>>>(ent, entb, bases1, root1, bases2, root2, rel,
                                     x1, wt1, wt2, relb, out);

    int fgrid = (N_NODES + NPB - 1) / NPB;   // 6250
    // layer 1: x1 -> x2 (relu)
    k_fused<<<fgrid, 256, 0, stream>>>(x1, edesc, offv, comp1, wt1, bias1, x2, 1);
    // layer 2: x2 -> x1 (no relu); x1 becomes xf
    k_fused<<<fgrid, 256, 0, stream>>>(x2, edesc, offv, comp2, wt2, bias2, x1, 0);
    // decode
    k_score<<<(NE + 15) / 16, 256, 0, stream>>>(x1, src, dst, edge_type, relb, out, NE);
}

// Round 7
// 570.924 us; speedup vs baseline: 1.6393x; 1.6393x over previous
//
#include <hip/hip_runtime.h>

#define N_NODES 100000
#define DIM     128
#define RR      100
#define NE      400000
#define NBLK    196    // ceil(N_NODES / 512)
#define NPB     32     // dst nodes per fused block (100000 = 3125 * 32, exact)

typedef float  floatx4 __attribute__((ext_vector_type(4)));
typedef __bf16 bf16x8  __attribute__((ext_vector_type(8)));

static __device__ __forceinline__ unsigned short f2b(float f) {
    union { float f; unsigned int i; } v; v.f = f;
    unsigned int u = v.i;
    unsigned int r = (u + 0x7fffu + ((u >> 16) & 1u)) >> 16;   // RNE
    return (unsigned short)r;
}
static __device__ __forceinline__ float b2f(unsigned int u16) {
    union { unsigned int i; float f; } v; v.i = u16 << 16; return v.f;
}
static __device__ __forceinline__ unsigned packbf(float a, float b) {
    return (unsigned)f2b(a) | ((unsigned)f2b(b) << 16);
}

// ---- per-dst degree ------------------------------------------------------
__global__ void k_deg(const int* __restrict__ dst, int* __restrict__ deg, int E) {
    int e = blockIdx.x * 256 + threadIdx.x;
    if (e < E) atomicAdd(&deg[dst[e]], 1);
}

// ---- 2-level exclusive scan over deg[N] ----------------------------------
__global__ void k_scan_block(const int* __restrict__ deg, int* __restrict__ bsum) {
    __shared__ int sm[256];
    int b = blockIdx.x, t = threadIdx.x;
    int i0 = b * 512 + 2 * t;
    int a = (i0     < N_NODES) ? deg[i0]     : 0;
    int c = (i0 + 1 < N_NODES) ? deg[i0 + 1] : 0;
    sm[t] = a + c;
    __syncthreads();
    for (int s = 128; s > 0; s >>= 1) { if (t < s) sm[t] += sm[t + s]; __syncthreads(); }
    if (t == 0) bsum[b] = sm[0];
}

__global__ void k_scan_top(const int* __restrict__ bsum, int* __restrict__ boff) {
    __shared__ int sm[256];
    int t = threadIdx.x;
    int v = (t < NBLK) ? bsum[t] : 0;
    sm[t] = v;
    __syncthreads();
    for (int s = 1; s < 256; s <<= 1) {
        int u = (t >= s) ? sm[t - s] : 0;
        __syncthreads();
        sm[t] += u;
        __syncthreads();
    }
    if (t < NBLK) boff[t] = sm[t] - v;   // exclusive
}

__global__ void k_scan_down(const int* __restrict__ deg, const int* __restrict__ boff,
                            int* __restrict__ off) {
    __shared__ int sm[256];
    int b = blockIdx.x, t = threadIdx.x;
    int i0 = b * 512 + 2 * t;
    int a = (i0     < N_NODES) ? deg[i0]     : 0;
    int c = (i0 + 1 < N_NODES) ? deg[i0 + 1] : 0;
    int ts = a + c;
    sm[t] = ts;
    __syncthreads();
    for (int s = 1; s < 256; s <<= 1) {
        int u = (t >= s) ? sm[t - s] : 0;
        __syncthreads();
        sm[t] += u;
        __syncthreads();
    }
    int base = boff[b] + (sm[t] - ts);
    if (i0     < N_NODES) off[i0]     = base;
    if (i0 + 1 < N_NODES) off[i0 + 1] = base + a;
    if (b == 0 && t == 0) off[N_NODES] = NE;
}

// ---- scatter edges into dst-sorted CSR: desc = {src, et, dst, norm} ------
__global__ void k_scatter(const int* __restrict__ src, const int* __restrict__ dst,
                          const int* __restrict__ et, const int* __restrict__ off,
                          int* __restrict__ cursor, int4* __restrict__ edesc, int E) {
    int e = blockIdx.x * 256 + threadIdx.x;
    if (e >= E) return;
    int d = dst[e];
    int pos = off[d] + atomicAdd(&cursor[d], 1);
    edesc[pos] = make_int4(src[e], et[e], d, 0);
}

// ---- schlichtkrull norm: one thread per CSR slot, O(deg) scan ------------
__global__ void k_norm2(const int* __restrict__ off, int4* __restrict__ edesc, int E) {
    int p = blockIdx.x * 256 + threadIdx.x;
    if (p >= E) return;
    int4 me = edesc[p];
    int p0 = off[me.z], p1 = off[me.z + 1];
    int c = 0;
    for (int j = p0; j < p1; ++j)
        c += (((const int*)edesc)[4 * j + 1] == me.y) ? 1 : 0;
    ((int*)edesc)[4 * p + 3] = __float_as_int(1.0f / (float)c);
}

// ---- fused preprocessing: x0 | weight transpose | rel bf16 | penalty -----
__global__ void k_pre(const float* __restrict__ ent, const float* __restrict__ entb,
                      const float* __restrict__ bases1, const float* __restrict__ root1,
                      const float* __restrict__ bases2, const float* __restrict__ root2,
                      const float* __restrict__ rel,
                      unsigned short* __restrict__ x1,
                      unsigned short* __restrict__ wt1, unsigned short* __restrict__ wt2,
                      unsigned short* __restrict__ relb, float* __restrict__ out) {
    int b = blockIdx.x, t = threadIdx.x;
    if (b < 50000) {                                   // x0 = relu(ent + bias)
        int i = b * 256 + t;
        float v = ent[i] + entb[i & (DIM - 1)];
        x1[i] = f2b(v > 0.0f ? v : 0.0f);
    } else if (b < 50320) {                            // wt[m][k]: bases|root
        int i = (b - 50000) * 256 + t;                 // 128*640
        int m = i / 640, k = i - m * 640;
        float v1, v2;
        if (k < 512) {
            int bb = k >> 7, kin = k & 127;
            v1 = bases1[(bb * 128 + kin) * 128 + m];
            v2 = bases2[(bb * 128 + kin) * 128 + m];
        } else {
            int kin = k - 512;
            v1 = root1[kin * 128 + m];
            v2 = root2[kin * 128 + m];
        }
        wt1[i] = f2b(v1);
        wt2[i] = f2b(v2);
    } else if (b < 50370) {                            // rel -> bf16
        int i = (b - 50320) * 256 + t;                 // 12800
        relb[i] = f2b(rel[i]);
    } else {                                           // penalty
        __shared__ float sm[256];
        float v = 0.0f;
        for (int i = t; i < RR * DIM; i += 256) { float x = rel[i]; v += x * x; }
        sm[t] = v;
        __syncthreads();
        for (int s = 128; s > 0; s >>= 1) {
            if (t < s) sm[t] += sm[t + s];
            __syncthreads();
        }
        if (t == 0) out[NE] = sm[0];
    }
}

// ---- fused aggregate + GEMM: no atomics, register accumulation -----------
// Block = 512 thr (8 waves), 32 dst nodes; each wave OWNS 4 consecutive
// nodes. Phase A: 16-edge batches, 16 prefetched gathers (readlane bases),
// fp32 register acc (wave-uniform row branch), single bf16 LDS write per
// (row,chunk). Phase B: MFMA K=640; S-chunks from swizzled LDS, X direct
// from global, WT from L2.
#define ACC(A) { A[0].x += w0 * xv0; A[0].y += w0 * xv1; \
                 A[1].x += w1 * xv0; A[1].y += w1 * xv1; \
                 A[2].x += w2 * xv0; A[2].y += w2 * xv1; \
                 A[3].x += w3 * xv0; A[3].y += w3 * xv1; }

__global__ __launch_bounds__(512, 4) void k_fused(const unsigned short* __restrict__ X,
                                                  const int4* __restrict__ edesc,
                                                  const int* __restrict__ off,
                                                  const float* __restrict__ comp,
                                                  const unsigned short* __restrict__ WT,
                                                  const float* __restrict__ bias,
                                                  unsigned short* __restrict__ out,
                                                  int do_relu) {
    __shared__ __align__(16) unsigned short Sacc[4 * NPB * 128];   // 32 KB, 4 planes
    __shared__ float4 Cs[RR];                                      // 1.6 KB

    const int t = threadIdx.x, wid = t >> 6, lane = t & 63;
    const int rbase = blockIdx.x * NPB;

    if (t < RR) Cs[t] = ((const float4*)comp)[t];
    __syncthreads();

    // ---------------- phase A: wave owns rows [nbase, nbase+4) ----------------
    {
        const int nbase = rbase + wid * 4;
        const int lo = off[nbase], hi = off[nbase + 4];
        float2 a0[4], a1[4], a2[4], a3[4];
#pragma unroll
        for (int c = 0; c < 4; ++c) {
            a0[c] = make_float2(0.f, 0.f); a1[c] = make_float2(0.f, 0.f);
            a2[c] = make_float2(0.f, 0.f); a3[c] = make_float2(0.f, 0.f);
        }
        for (int base = lo; base < hi; base += 16) {
            int cnt = hi - base; if (cnt > 16) cnt = 16;
            int4 md = edesc[base + (lane & 15)];
            unsigned xp[16];
#pragma unroll
            for (int u = 0; u < 16; ++u) {             // 16 independent gathers
                int jc = (u < cnt) ? u : 0;
                int s = (int)__builtin_amdgcn_readlane((unsigned)md.x, (unsigned)jc);
                xp[u] = *(const unsigned*)(X + (size_t)s * 128 + 2 * lane);
            }
#pragma unroll
            for (int u = 0; u < 16; ++u) {
                if (u < cnt) {                         // wave-uniform guard
                    int row = (int)__builtin_amdgcn_readlane((unsigned)md.z, (unsigned)u) - nbase;
                    int tt  = (int)__builtin_amdgcn_readlane((unsigned)md.y, (unsigned)u);
                    float w = __int_as_float(__builtin_amdgcn_readlane((unsigned)md.w, (unsigned)u));
                    float4 cc = Cs[tt];
                    float xv0 = b2f(xp[u] & 0xffffu), xv1 = b2f(xp[u] >> 16);
                    float w0 = w * cc.x, w1 = w * cc.y, w2 = w * cc.z, w3 = w * cc.w;
                    if      (row == 0) ACC(a0)
                    else if (row == 1) ACC(a1)
                    else if (row == 2) ACC(a2)
                    else               ACC(a3)
                }
            }
        }
        // write 4 rows x 4 chunks, bf16-packed, xor-swizzled 16B chunks
        const int sw16 = lane >> 2, wo = 2 * (lane & 3);
#pragma unroll
        for (int r = 0; r < 4; ++r) {
            int R = wid * 4 + r;
            unsigned bo = (unsigned)(R * 128 + ((sw16 ^ (R & 15)) << 3) + wo);
            float2* A = (r == 0) ? a0 : (r == 1) ? a1 : (r == 2) ? a2 : a3;
#pragma unroll
            for (int c = 0; c < 4; ++c)
                *(unsigned*)(Sacc + c * (NPB * 128) + bo) = packbf(A[c].x, A[c].y);
        }
    }
    __syncthreads();

    // ---------------- phase B: MFMA, m=32 n=128 K=640 ----------------
    const int quad = lane >> 4, lr = lane & 15;
    const int wr = wid & 1, wc = wid >> 1;             // 2 m-tiles x 4 n-slices
    floatx4 acc[2];
    acc[0] = (floatx4)0.0f; acc[1] = (floatx4)0.0f;

#pragma unroll
    for (int kc = 0; kc < 5; ++kc) {
#pragma unroll
        for (int ks = 0; ks < 4; ++ks) {
            bf16x8 a, b0, b1;
            int R = wr * 16 + lr;
            if (kc < 4) {
                int ch = ((ks * 4 + quad) ^ (R & 15)) << 3;
                a = *(const bf16x8*)(Sacc + kc * (NPB * 128) + R * 128 + ch);
            } else {
                int grow = rbase + R;
                if (grow >= N_NODES) grow = N_NODES - 1;
                a = *(const bf16x8*)(X + (size_t)grow * 128 + ks * 32 + quad * 8);
            }
            b0 = *(const bf16x8*)(WT + (size_t)(wc * 32 + lr) * 640      + kc * 128 + ks * 32 + quad * 8);
            b1 = *(const bf16x8*)(WT + (size_t)(wc * 32 + 16 + lr) * 640 + kc * 128 + ks * 32 + quad * 8);
            acc[0] = __builtin_amdgcn_mfma_f32_16x16x32_bf16(a, b0, acc[0], 0, 0, 0);
            acc[1] = __builtin_amdgcn_mfma_f32_16x16x32_bf16(a, b1, acc[1], 0, 0, 0);
        }
    }

    // C/D layout: col=lane&15, row=quad*4+reg  [m89/m91-verified]
#pragma unroll
    for (int reg = 0; reg < 4; ++reg) {
        int R = wr * 16 + quad * 4 + reg;
        int grow = rbase + R;
        if (grow >= N_NODES) continue;
#pragma unroll
        for (int nj = 0; nj < 2; ++nj) {
            int n = wc * 32 + nj * 16 + lr;
            float v = acc[nj][reg] + bias[n];
            if (do_relu) v = v > 0.0f ? v : 0.0f;
            out[(size_t)grow * 128 + n] = f2b(v);
        }
    }
}

// ---- DistMult score: 16 lanes per edge, bf16 gathers ---------------------
__global__ __launch_bounds__(256) void k_score(const unsigned short* __restrict__ xf,
                                               const int* __restrict__ src, const int* __restrict__ dst,
                                               const int* __restrict__ et,
                                               const unsigned short* __restrict__ relb,
                                               float* __restrict__ out, int E) {
    int g = threadIdx.x >> 4, li = threadIdx.x & 15;
    int e = blockIdx.x * 16 + g;
    if (e >= E) return;
    int s = src[e], d = dst[e], tt = et[e];
    uint4 au = *(const uint4*)(xf + (size_t)s * 128 + li * 8);
    uint4 bu = *(const uint4*)(xf + (size_t)d * 128 + li * 8);
    uint4 ru = *(const uint4*)(relb + (size_t)tt * 128 + li * 8);
    float v;
    v  = b2f(au.x & 0xffffu) * b2f(ru.x & 0xffffu) * b2f(bu.x & 0xffffu);
    v += b2f(au.x >> 16)     * b2f(ru.x >> 16)     * b2f(bu.x >> 16);
    v += b2f(au.y & 0xffffu) * b2f(ru.y & 0xffffu) * b2f(bu.y & 0xffffu);
    v += b2f(au.y >> 16)     * b2f(ru.y >> 16)     * b2f(bu.y >> 16);
    v += b2f(au.z & 0xffffu) * b2f(ru.z & 0xffffu) * b2f(bu.z & 0xffffu);
    v += b2f(au.z >> 16)     * b2f(ru.z >> 16)     * b2f(bu.z >> 16);
    v += b2f(au.w & 0xffffu) * b2f(ru.w & 0xffffu) * b2f(bu.w & 0xffffu);
    v += b2f(au.w >> 16)     * b2f(ru.w >> 16)     * b2f(bu.w >> 16);
    v += __shfl_xor(v, 8, 16);
    v += __shfl_xor(v, 4, 16);
    v += __shfl_xor(v, 2, 16);
    v += __shfl_xor(v, 1, 16);
    if (li == 0) out[e] = v;
}

extern "C" void kernel_launch(void* const* d_in, const int* in_sizes, int n_in,
                              void* d_out, int out_size, void* d_ws, size_t ws_size,
                              hipStream_t stream) {
    (void)in_sizes; (void)n_in; (void)out_size; (void)ws_size;
    const int* edge_index = (const int*)d_in[0];
    const int* edge_type  = (const int*)d_in[1];
    const float* ent    = (const float*)d_in[2];
    const float* entb   = (const float*)d_in[3];
    const float* bases1 = (const float*)d_in[4];
    const float* comp1  = (const float*)d_in[5];
    const float* root1  = (const float*)d_in[6];
    const float* bias1  = (const float*)d_in[7];
    const float* bases2 = (const float*)d_in[8];
    const float* comp2  = (const float*)d_in[9];
    const float* root2  = (const float*)d_in[10];
    const float* bias2  = (const float*)d_in[11];
    const float* rel    = (const float*)d_in[12];
    const int* src = edge_index;
    const int* dst = edge_index + NE;

    char* ws = (char*)d_ws;
    size_t off_b = 0;
    auto alloc = [&](size_t bytes) { void* p = ws + off_b; off_b = (off_b + bytes + 255) & ~(size_t)255; return p; };

    unsigned short* x1   = (unsigned short*)alloc((size_t)N_NODES * 128 * 2);  // 25.6 MB
    unsigned short* x2   = (unsigned short*)alloc((size_t)N_NODES * 128 * 2);  // 25.6 MB
    unsigned short* wt1  = (unsigned short*)alloc(128 * 640 * 2);
    unsigned short* wt2  = (unsigned short*)alloc(128 * 640 * 2);
    unsigned short* relb = (unsigned short*)alloc(RR * DIM * 2);
    int*   deg    = (int*)alloc((size_t)N_NODES * 4);
    int*   cursor = (int*)alloc((size_t)N_NODES * 4);
    int*   offv   = (int*)alloc((size_t)(N_NODES + 1) * 4);
    int*   bsum   = (int*)alloc(NBLK * 4);
    int*   boff   = (int*)alloc(NBLK * 4);
    int4*  edesc  = (int4*)alloc((size_t)(NE + 64) * 16);                      // 6.4 MB + pad

    float* out = (float*)d_out;

    hipMemsetAsync(deg, 0, (size_t)N_NODES * 4, stream);
    hipMemsetAsync(cursor, 0, (size_t)N_NODES * 4, stream);

    k_deg<<<(NE + 255) / 256, 256, 0, stream>>>(dst, deg, NE);
    k_scan_block<<<NBLK, 256, 0, stream>>>(deg, bsum);
    k_scan_top<<<1, 256, 0, stream>>>(bsum, boff);
    k_scan_down<<<NBLK, 256, 0, stream>>>(deg, boff, offv);
    k_scatter<<<(NE + 255) / 256, 256, 0, stream>>>(src, dst, edge_type, offv, cursor, edesc, NE);
    k_norm2<<<(NE + 255) / 256, 256, 0, stream>>>(offv, edesc, NE);
    k_pre<<<50371, 256, 0, stream>>>(ent, entb, bases1, root1, bases2, root2, rel,
                                     x1, wt1, wt2, relb, out);

    int fgrid = N_NODES / NPB;   // 3125 (exact)
    // layer 1: x1 -> x2 (relu)
    k_fused<<<fgrid, 512, 0, stream>>>(x1, edesc, offv, comp1, wt1, bias1, x2, 1);
    // layer 2: x2 -> x1 (no relu); x1 becomes xf
    k_fused<<<fgrid, 512, 0, stream>>>(x2, edesc, offv, comp2, wt2, bias2, x1, 0);
    // decode
    k_score<<<(NE + 15) / 16, 256, 0, stream>>>(x1, src, dst, edge_type, relb, out, NE);
}

// Round 8
// 442.903 us; speedup vs baseline: 2.1131x; 1.2891x over previous
//
#include <hip/hip_runtime.h>

#define N_NODES 100000
#define DIM     128
#define RR      100
#define NE      400000
#define NBLK    196    // ceil(N_NODES / 512)

typedef float  floatx4 __attribute__((ext_vector_type(4)));
typedef __bf16 bf16x8  __attribute__((ext_vector_type(8)));

static __device__ __forceinline__ unsigned short f2b(float f) {
    union { float f; unsigned int i; } v; v.f = f;
    unsigned int u = v.i;
    unsigned int r = (u + 0x7fffu + ((u >> 16) & 1u)) >> 16;   // RNE
    return (unsigned short)r;
}
static __device__ __forceinline__ float b2f(unsigned int u16) {
    union { unsigned int i; float f; } v; v.i = u16 << 16; return v.f;
}
static __device__ __forceinline__ unsigned packbf(float a, float b) {
    return (unsigned)f2b(a) | ((unsigned)f2b(b) << 16);
}

// ---- per-dst degree ------------------------------------------------------
__global__ void k_deg(const int* __restrict__ dst, int* __restrict__ deg, int E) {
    int e = blockIdx.x * 256 + threadIdx.x;
    if (e < E) atomicAdd(&deg[dst[e]], 1);
}

// ---- 2-level exclusive scan over deg[N] ----------------------------------
__global__ void k_scan_block(const int* __restrict__ deg, int* __restrict__ bsum) {
    __shared__ int sm[256];
    int b = blockIdx.x, t = threadIdx.x;
    int i0 = b * 512 + 2 * t;
    int a = (i0     < N_NODES) ? deg[i0]     : 0;
    int c = (i0 + 1 < N_NODES) ? deg[i0 + 1] : 0;
    sm[t] = a + c;
    __syncthreads();
    for (int s = 128; s > 0; s >>= 1) { if (t < s) sm[t] += sm[t + s]; __syncthreads(); }
    if (t == 0) bsum[b] = sm[0];
}

__global__ void k_scan_top(const int* __restrict__ bsum, int* __restrict__ boff) {
    __shared__ int sm[256];
    int t = threadIdx.x;
    int v = (t < NBLK) ? bsum[t] : 0;
    sm[t] = v;
    __syncthreads();
    for (int s = 1; s < 256; s <<= 1) {
        int u = (t >= s) ? sm[t - s] : 0;
        __syncthreads();
        sm[t] += u;
        __syncthreads();
    }
    if (t < NBLK) boff[t] = sm[t] - v;   // exclusive
}

__global__ void k_scan_down(const int* __restrict__ deg, const int* __restrict__ boff,
                            int* __restrict__ off) {
    __shared__ int sm[256];
    int b = blockIdx.x, t = threadIdx.x;
    int i0 = b * 512 + 2 * t;
    int a = (i0     < N_NODES) ? deg[i0]     : 0;
    int c = (i0 + 1 < N_NODES) ? deg[i0 + 1] : 0;
    int ts = a + c;
    sm[t] = ts;
    __syncthreads();
    for (int s = 1; s < 256; s <<= 1) {
        int u = (t >= s) ? sm[t - s] : 0;
        __syncthreads();
        sm[t] += u;
        __syncthreads();
    }
    int base = boff[b] + (sm[t] - ts);
    if (i0     < N_NODES) off[i0]     = base;
    if (i0 + 1 < N_NODES) off[i0 + 1] = base + a;
    if (b == 0 && t == 0) off[N_NODES] = NE;
}

// ---- scatter edges into dst-sorted CSR: desc = {src, et, dst, norm} ------
__global__ void k_scatter(const int* __restrict__ src, const int* __restrict__ dst,
                          const int* __restrict__ et, const int* __restrict__ off,
                          int* __restrict__ cursor, int4* __restrict__ edesc, int E) {
    int e = blockIdx.x * 256 + threadIdx.x;
    if (e >= E) return;
    int d = dst[e];
    int pos = off[d] + atomicAdd(&cursor[d], 1);
    edesc[pos] = make_int4(src[e], et[e], d, 0);
}

// ---- schlichtkrull norm: one thread per CSR slot, O(deg) scan ------------
__global__ void k_norm2(const int* __restrict__ off, int4* __restrict__ edesc, int E) {
    int p = blockIdx.x * 256 + threadIdx.x;
    if (p >= E) return;
    int4 me = edesc[p];
    int p0 = off[me.z], p1 = off[me.z + 1];
    int c = 0;
    for (int j = p0; j < p1; ++j)
        c += (((const int*)edesc)[4 * j + 1] == me.y) ? 1 : 0;
    ((int*)edesc)[4 * p + 3] = __float_as_int(1.0f / (float)c);
}

// ---- fused preprocessing: x0 | weight transpose | rel bf16 | penalty -----
__global__ void k_pre(const float* __restrict__ ent, const float* __restrict__ entb,
                      const float* __restrict__ bases1, const float* __restrict__ root1,
                      const float* __restrict__ bases2, const float* __restrict__ root2,
                      const float* __restrict__ rel,
                      unsigned short* __restrict__ x1,
                      unsigned short* __restrict__ wt1, unsigned short* __restrict__ wt2,
                      unsigned short* __restrict__ relb, float* __restrict__ out) {
    int b = blockIdx.x, t = threadIdx.x;
    if (b < 50000) {                                   // x0 = relu(ent + bias)
        int i = b * 256 + t;
        float v = ent[i] + entb[i & (DIM - 1)];
        x1[i] = f2b(v > 0.0f ? v : 0.0f);
    } else if (b < 50320) {                            // wt[m][k]: bases|root
        int i = (b - 50000) * 256 + t;                 // 128*640
        int m = i / 640, k = i - m * 640;
        float v1, v2;
        if (k < 512) {
            int bb = k >> 7, kin = k & 127;
            v1 = bases1[(bb * 128 + kin) * 128 + m];
            v2 = bases2[(bb * 128 + kin) * 128 + m];
        } else {
            int kin = k - 512;
            v1 = root1[kin * 128 + m];
            v2 = root2[kin * 128 + m];
        }
        wt1[i] = f2b(v1);
        wt2[i] = f2b(v2);
    } else if (b < 50370) {                            // rel -> bf16
        int i = (b - 50320) * 256 + t;                 // 12800
        relb[i] = f2b(rel[i]);
    } else {                                           // penalty
        __shared__ float sm[256];
        float v = 0.0f;
        for (int i = t; i < RR * DIM; i += 256) { float x = rel[i]; v += x * x; }
        sm[t] = v;
        __syncthreads();
        for (int s = 128; s > 0; s >>= 1) {
            if (t < s) sm[t] += sm[t + s];
            __syncthreads();
        }
        if (t == 0) out[NE] = sm[0];
    }
}

// ---- pre-projection aggregation: one wave per dst node, 4-deep prefetch --
// s[d, b*128 + c] = sum_e norm_e * comp[et_e, b] * x[src_e, c]   (bf16 out)
__global__ __launch_bounds__(256) void k_agg(const unsigned short* __restrict__ X,
                                             const int4* __restrict__ edesc,
                                             const int* __restrict__ off,
                                             const float* __restrict__ comp,
                                             unsigned short* __restrict__ S) {
    int wid = threadIdx.x >> 6, lane = threadIdx.x & 63;
    int d = blockIdx.x * 4 + wid;
    if (d >= N_NODES) return;
    int p0 = off[d], p1 = off[d + 1];
    float2 acc[4];
#pragma unroll
    for (int b = 0; b < 4; ++b) acc[b] = make_float2(0.0f, 0.0f);

    for (int p = p0; p < p1; p += 4) {
        int cnt = p1 - p; if (cnt > 4) cnt = 4;
        int4 e[4];
        unsigned xg[4];
#pragma unroll
        for (int k = 0; k < 4; ++k) e[k] = edesc[p + ((k < cnt) ? k : 0)];
#pragma unroll
        for (int k = 0; k < 4; ++k)                   // 4 independent gathers
            xg[k] = *(const unsigned*)(X + (size_t)e[k].x * 128 + 2 * lane);
#pragma unroll
        for (int k = 0; k < 4; ++k) {
            if (k < cnt) {
                float w = __int_as_float(e[k].w);
                float4 cc = *(const float4*)(comp + e[k].y * 4);
                float x0 = b2f(xg[k] & 0xffffu), x1 = b2f(xg[k] >> 16);
                float w0 = w * cc.x, w1 = w * cc.y, w2 = w * cc.z, w3 = w * cc.w;
                acc[0].x += w0 * x0; acc[0].y += w0 * x1;
                acc[1].x += w1 * x0; acc[1].y += w1 * x1;
                acc[2].x += w2 * x0; acc[2].y += w2 * x1;
                acc[3].x += w3 * x0; acc[3].y += w3 * x1;
            }
        }
    }
    size_t base = (size_t)d * 512 + 2 * lane;
#pragma unroll
    for (int b = 0; b < 4; ++b)
        *(unsigned*)(S + base + b * 128) = packbf(acc[b].x, acc[b].y);
}

// ---- GEMM: out[N,128] = relu?([S|X][N,640] @ WT^T + bias), bf16 out ------
// (r3-verified kernel, verbatim)
__global__ __launch_bounds__(256) void k_gemm2(const unsigned short* __restrict__ S,
                                               const unsigned short* __restrict__ X,
                                               const unsigned short* __restrict__ WT,
                                               const float* __restrict__ bias,
                                               unsigned short* __restrict__ out,
                                               int do_relu) {
    __shared__ __align__(16) unsigned short As[128 * 128];
    __shared__ __align__(16) unsigned short Bs[128 * 128];

    const int t = threadIdx.x;
    const int rbase = blockIdx.x * 128;
    const int wid = t >> 6, lane = t & 63;
    const int quad = lane >> 4, lr = lane & 15;
    const int wr = wid >> 1, wc = wid & 1;

    floatx4 acc[4][4];
#pragma unroll
    for (int i = 0; i < 4; ++i)
#pragma unroll
        for (int j = 0; j < 4; ++j) acc[i][j] = (floatx4)0.0f;

    for (int kc = 0; kc < 5; ++kc) {
        const unsigned short* abase;
        size_t astride;
        if (kc < 4) { abase = S + kc * 128; astride = 512; }
        else        { abase = X;            astride = 128; }
#pragma unroll
        for (int i = 0; i < 8; ++i) {
            int idx = i * 256 + t;
            int row = idx >> 4, ch = idx & 15;
            int sch = (ch ^ (row & 15)) << 3;
            uint4 v = make_uint4(0u, 0u, 0u, 0u);
            int grow = rbase + row;
            if (grow < N_NODES) v = *(const uint4*)(abase + (size_t)grow * astride + ch * 8);
            *(uint4*)(As + row * 128 + sch) = v;
            uint4 w = *(const uint4*)(WT + (size_t)row * 640 + kc * 128 + ch * 8);
            *(uint4*)(Bs + row * 128 + sch) = w;
        }
        __syncthreads();
#pragma unroll
        for (int ks = 0; ks < 4; ++ks) {
            bf16x8 a[4], b[4];
#pragma unroll
            for (int i = 0; i < 4; ++i) {
                int ar = wr * 64 + i * 16 + lr;
                int br = wc * 64 + i * 16 + lr;
                int sch = ((ks * 4 + quad) ^ lr) << 3;
                a[i] = *(const bf16x8*)(As + ar * 128 + sch);
                b[i] = *(const bf16x8*)(Bs + br * 128 + sch);
            }
#pragma unroll
            for (int i = 0; i < 4; ++i)
#pragma unroll
                for (int j = 0; j < 4; ++j)
                    acc[i][j] = __builtin_amdgcn_mfma_f32_16x16x32_bf16(a[i], b[j], acc[i][j], 0, 0, 0);
        }
        __syncthreads();
    }

    // C/D layout: col=lane&15, row=quad*4+reg  [m89/m91-verified]
#pragma unroll
    for (int i = 0; i < 4; ++i) {
        int r0 = rbase + wr * 64 + i * 16 + quad * 4;
#pragma unroll
        for (int reg = 0; reg < 4; ++reg) {
            int grow = r0 + reg;
            if (grow >= N_NODES) continue;
#pragma unroll
            for (int j = 0; j < 4; ++j) {
                int col = wc * 64 + j * 16 + lr;
                float v = acc[i][j][reg] + bias[col];
                if (do_relu) v = v > 0.0f ? v : 0.0f;
                out[(size_t)grow * 128 + col] = f2b(v);
            }
        }
    }
}

// ---- DistMult score: 16 lanes per edge, bf16 gathers ---------------------
__global__ __launch_bounds__(256) void k_score(const unsigned short* __restrict__ xf,
                                               const int* __restrict__ src, const int* __restrict__ dst,
                                               const int* __restrict__ et,
                                               const unsigned short* __restrict__ relb,
                                               float* __restrict__ out, int E) {
    int g = threadIdx.x >> 4, li = threadIdx.x & 15;
    int e = blockIdx.x * 16 + g;
    if (e >= E) return;
    int s = src[e], d = dst[e], tt = et[e];
    uint4 au = *(const uint4*)(xf + (size_t)s * 128 + li * 8);
    uint4 bu = *(const uint4*)(xf + (size_t)d * 128 + li * 8);
    uint4 ru = *(const uint4*)(relb + (size_t)tt * 128 + li * 8);
    float v;
    v  = b2f(au.x & 0xffffu) * b2f(ru.x & 0xffffu) * b2f(bu.x & 0xffffu);
    v += b2f(au.x >> 16)     * b2f(ru.x >> 16)     * b2f(bu.x >> 16);
    v += b2f(au.y & 0xffffu) * b2f(ru.y & 0xffffu) * b2f(bu.y & 0xffffu);
    v += b2f(au.y >> 16)     * b2f(ru.y >> 16)     * b2f(bu.y >> 16);
    v += b2f(au.z & 0xffffu) * b2f(ru.z & 0xffffu) * b2f(bu.z & 0xffffu);
    v += b2f(au.z >> 16)     * b2f(ru.z >> 16)     * b2f(bu.z >> 16);
    v += b2f(au.w & 0xffffu) * b2f(ru.w & 0xffffu) * b2f(bu.w & 0xffffu);
    v += b2f(au.w >> 16)     * b2f(ru.w >> 16)     * b2f(bu.w >> 16);
    v += __shfl_xor(v, 8, 16);
    v += __shfl_xor(v, 4, 16);
    v += __shfl_xor(v, 2, 16);
    v += __shfl_xor(v, 1, 16);
    if (li == 0) out[e] = v;
}

extern "C" void kernel_launch(void* const* d_in, const int* in_sizes, int n_in,
                              void* d_out, int out_size, void* d_ws, size_t ws_size,
                              hipStream_t stream) {
    (void)in_sizes; (void)n_in; (void)out_size; (void)ws_size;
    const int* edge_index = (const int*)d_in[0];
    const int* edge_type  = (const int*)d_in[1];
    const float* ent    = (const float*)d_in[2];
    const float* entb   = (const float*)d_in[3];
    const float* bases1 = (const float*)d_in[4];
    const float* comp1  = (const float*)d_in[5];
    const float* root1  = (const float*)d_in[6];
    const float* bias1  = (const float*)d_in[7];
    const float* bases2 = (const float*)d_in[8];
    const float* comp2  = (const float*)d_in[9];
    const float* root2  = (const float*)d_in[10];
    const float* bias2  = (const float*)d_in[11];
    const float* rel    = (const float*)d_in[12];
    const int* src = edge_index;
    const int* dst = edge_index + NE;

    char* ws = (char*)d_ws;
    size_t off_b = 0;
    auto alloc = [&](size_t bytes) { void* p = ws + off_b; off_b = (off_b + bytes + 255) & ~(size_t)255; return p; };

    unsigned short* sbuf = (unsigned short*)alloc((size_t)N_NODES * 512 * 2);  // 102.4 MB
    unsigned short* x1   = (unsigned short*)alloc((size_t)N_NODES * 128 * 2);  // 25.6 MB
    unsigned short* x2   = (unsigned short*)alloc((size_t)N_NODES * 128 * 2);  // 25.6 MB
    unsigned short* wt1  = (unsigned short*)alloc(128 * 640 * 2);
    unsigned short* wt2  = (unsigned short*)alloc(128 * 640 * 2);
    unsigned short* relb = (unsigned short*)alloc(RR * DIM * 2);
    int*   deg    = (int*)alloc((size_t)N_NODES * 4);
    int*   cursor = (int*)alloc((size_t)N_NODES * 4);
    int*   offv   = (int*)alloc((size_t)(N_NODES + 1) * 4);
    int*   bsum   = (int*)alloc(NBLK * 4);
    int*   boff   = (int*)alloc(NBLK * 4);
    int4*  edesc  = (int4*)alloc((size_t)(NE + 64) * 16);                      // 6.4 MB + pad

    float* out = (float*)d_out;

    hipMemsetAsync(deg, 0, (size_t)N_NODES * 4, stream);
    hipMemsetAsync(cursor, 0, (size_t)N_NODES * 4, stream);

    k_deg<<<(NE + 255) / 256, 256, 0, stream>>>(dst, deg, NE);
    k_scan_block<<<NBLK, 256, 0, stream>>>(deg, bsum);
    k_scan_top<<<1, 256, 0, stream>>>(bsum, boff);
    k_scan_down<<<NBLK, 256, 0, stream>>>(deg, boff, offv);
    k_scatter<<<(NE + 255) / 256, 256, 0, stream>>>(src, dst, edge_type, offv, cursor, edesc, NE);
    k_norm2<<<(NE + 255) / 256, 256, 0, stream>>>(offv, edesc, NE);
    k_pre<<<50371, 256, 0, stream>>>(ent, entb, bases1, root1, bases2, root2, rel,
                                     x1, wt1, wt2, relb, out);

    int ggrid = (N_NODES + 127) / 128;   // 782
    // layer 1: x1 -> x2 (relu)
    k_agg<<<(N_NODES + 3) / 4, 256, 0, stream>>>(x1, edesc, offv, comp1, sbuf);
    k_gemm2<<<ggrid, 256, 0, stream>>>(sbuf, x1, wt1, bias1, x2, 1);
    // layer 2: x2 -> x1 (no relu); x1 becomes xf
    k_agg<<<(N_NODES + 3) / 4, 256, 0, stream>>>(x2, edesc, offv, comp2, sbuf);
    k_gemm2<<<ggrid, 256, 0, stream>>>(sbuf, x2, wt2, bias2, x1, 0);
    // decode
    k_score<<<(NE + 15) / 16, 256, 0, stream>>>(x1, src, dst, edge_type, relb, out, NE);
}

// Round 9
// 400.051 us; speedup vs baseline: 2.3395x; 1.1071x over previous
//
#include <hip/hip_runtime.h>

#define N_NODES 100000
#define DIM     128
#define RR      100
#define NE      400000
#define NBLK    196    // ceil(N_NODES / 512)
#define NPB     32     // dst nodes per fused block (100000 = 3125 * 32, exact)

typedef float  floatx4 __attribute__((ext_vector_type(4)));
typedef __bf16 bf16x8  __attribute__((ext_vector_type(8)));

static __device__ __forceinline__ unsigned short f2b(float f) {
    union { float f; unsigned int i; } v; v.f = f;
    unsigned int u = v.i;
    unsigned int r = (u + 0x7fffu + ((u >> 16) & 1u)) >> 16;   // RNE
    return (unsigned short)r;
}
static __device__ __forceinline__ float b2f(unsigned int u16) {
    union { unsigned int i; float f; } v; v.i = u16 << 16; return v.f;
}
static __device__ __forceinline__ unsigned packbf(float a, float b) {
    return (unsigned)f2b(a) | ((unsigned)f2b(b) << 16);
}

// ---- per-dst degree ------------------------------------------------------
__global__ void k_deg(const int* __restrict__ dst, int* __restrict__ deg, int E) {
    int e = blockIdx.x * 256 + threadIdx.x;
    if (e < E) atomicAdd(&deg[dst[e]], 1);
}

// ---- 2-level exclusive scan over deg[N] ----------------------------------
__global__ void k_scan_block(const int* __restrict__ deg, int* __restrict__ bsum) {
    __shared__ int sm[256];
    int b = blockIdx.x, t = threadIdx.x;
    int i0 = b * 512 + 2 * t;
    int a = (i0     < N_NODES) ? deg[i0]     : 0;
    int c = (i0 + 1 < N_NODES) ? deg[i0 + 1] : 0;
    sm[t] = a + c;
    __syncthreads();
    for (int s = 128; s > 0; s >>= 1) { if (t < s) sm[t] += sm[t + s]; __syncthreads(); }
    if (t == 0) bsum[b] = sm[0];
}

__global__ void k_scan_top(const int* __restrict__ bsum, int* __restrict__ boff) {
    __shared__ int sm[256];
    int t = threadIdx.x;
    int v = (t < NBLK) ? bsum[t] : 0;
    sm[t] = v;
    __syncthreads();
    for (int s = 1; s < 256; s <<= 1) {
        int u = (t >= s) ? sm[t - s] : 0;
        __syncthreads();
        sm[t] += u;
        __syncthreads();
    }
    if (t < NBLK) boff[t] = sm[t] - v;   // exclusive
}

__global__ void k_scan_down(const int* __restrict__ deg, const int* __restrict__ boff,
                            int* __restrict__ off) {
    __shared__ int sm[256];
    int b = blockIdx.x, t = threadIdx.x;
    int i0 = b * 512 + 2 * t;
    int a = (i0     < N_NODES) ? deg[i0]     : 0;
    int c = (i0 + 1 < N_NODES) ? deg[i0 + 1] : 0;
    int ts = a + c;
    sm[t] = ts;
    __syncthreads();
    for (int s = 1; s < 256; s <<= 1) {
        int u = (t >= s) ? sm[t - s] : 0;
        __syncthreads();
        sm[t] += u;
        __syncthreads();
    }
    int base = boff[b] + (sm[t] - ts);
    if (i0     < N_NODES) off[i0]     = base;
    if (i0 + 1 < N_NODES) off[i0 + 1] = base + a;
    if (b == 0 && t == 0) off[N_NODES] = NE;
}

// ---- scatter edges into dst-sorted CSR: desc = {src, et, dst, norm} ------
__global__ void k_scatter(const int* __restrict__ src, const int* __restrict__ dst,
                          const int* __restrict__ et, const int* __restrict__ off,
                          int* __restrict__ cursor, int4* __restrict__ edesc, int E) {
    int e = blockIdx.x * 256 + threadIdx.x;
    if (e >= E) return;
    int d = dst[e];
    int pos = off[d] + atomicAdd(&cursor[d], 1);
    edesc[pos] = make_int4(src[e], et[e], d, 0);
}

// ---- schlichtkrull norm: one thread per CSR slot, O(deg) scan ------------
__global__ void k_norm2(const int* __restrict__ off, int4* __restrict__ edesc, int E) {
    int p = blockIdx.x * 256 + threadIdx.x;
    if (p >= E) return;
    int4 me = edesc[p];
    int p0 = off[me.z], p1 = off[me.z + 1];
    int c = 0;
    for (int j = p0; j < p1; ++j)
        c += (((const int*)edesc)[4 * j + 1] == me.y) ? 1 : 0;
    ((int*)edesc)[4 * p + 3] = __float_as_int(1.0f / (float)c);
}

// ---- fused preprocessing: x0 | weight transpose | rel bf16 | penalty -----
__global__ void k_pre(const float* __restrict__ ent, const float* __restrict__ entb,
                      const float* __restrict__ bases1, const float* __restrict__ root1,
                      const float* __restrict__ bases2, const float* __restrict__ root2,
                      const float* __restrict__ rel,
                      unsigned short* __restrict__ x1,
                      unsigned short* __restrict__ wt1, unsigned short* __restrict__ wt2,
                      unsigned short* __restrict__ relb, float* __restrict__ out) {
    int b = blockIdx.x, t = threadIdx.x;
    if (b < 50000) {                                   // x0 = relu(ent + bias)
        int i = b * 256 + t;
        float v = ent[i] + entb[i & (DIM - 1)];
        x1[i] = f2b(v > 0.0f ? v : 0.0f);
    } else if (b < 50320) {                            // wt[m][k]: bases|root
        int i = (b - 50000) * 256 + t;                 // 128*640
        int m = i / 640, k = i - m * 640;
        float v1, v2;
        if (k < 512) {
            int bb = k >> 7, kin = k & 127;
            v1 = bases1[(bb * 128 + kin) * 128 + m];
            v2 = bases2[(bb * 128 + kin) * 128 + m];
        } else {
            int kin = k - 512;
            v1 = root1[kin * 128 + m];
            v2 = root2[kin * 128 + m];
        }
        wt1[i] = f2b(v1);
        wt2[i] = f2b(v2);
    } else if (b < 50370) {                            // rel -> bf16
        int i = (b - 50320) * 256 + t;                 // 12800
        relb[i] = f2b(rel[i]);
    } else {                                           // penalty
        __shared__ float sm[256];
        float v = 0.0f;
        for (int i = t; i < RR * DIM; i += 256) { float x = rel[i]; v += x * x; }
        sm[t] = v;
        __syncthreads();
        for (int s = 128; s > 0; s >>= 1) {
            if (t < s) sm[t] += sm[t + s];
            __syncthreads();
        }
        if (t == 0) out[NE] = sm[0];
    }
}

// ---- fused aggregate + GEMM v3 -------------------------------------------
// Block = 512 thr (8 waves), 32 dst nodes; wave owns 4 consecutive nodes.
// Phase A (r7-verified): 16-edge batches, 16 prefetched gathers, register
// fp32 acc, single bf16 LDS write per (row,chunk). Phase B: MFMA K=640 with
// the B chunk staged cooperatively into LDS per kc (the r7 fix: no per-wave
// global B loads), X fragments prefetched to registers for kc=4.
#define ACC(A) { A[0].x += w0 * xv0; A[0].y += w0 * xv1; \
                 A[1].x += w1 * xv0; A[1].y += w1 * xv1; \
                 A[2].x += w2 * xv0; A[2].y += w2 * xv1; \
                 A[3].x += w3 * xv0; A[3].y += w3 * xv1; }

__global__ __launch_bounds__(512, 4) void k_fused(const unsigned short* __restrict__ X,
                                                  const int4* __restrict__ edesc,
                                                  const int* __restrict__ off,
                                                  const float* __restrict__ comp,
                                                  const unsigned short* __restrict__ WT,
                                                  const float* __restrict__ bias,
                                                  unsigned short* __restrict__ out,
                                                  int do_relu) {
    __shared__ __align__(16) unsigned short Sacc[4 * NPB * 128];   // 32 KB, 4 planes
    __shared__ __align__(16) unsigned short Bs[128 * 128];         // 32 KB, per-kc B chunk
    __shared__ float4 Cs[RR];                                      // 1.6 KB

    const int t = threadIdx.x, wid = t >> 6, lane = t & 63;
    const int rbase = blockIdx.x * NPB;

    if (t < RR) Cs[t] = ((const float4*)comp)[t];
    __syncthreads();

    // ---------------- phase A: wave owns rows [nbase, nbase+4) ----------------
    {
        const int nbase = rbase + wid * 4;
        const int lo = off[nbase], hi = off[nbase + 4];
        float2 a0[4], a1[4], a2[4], a3[4];
#pragma unroll
        for (int c = 0; c < 4; ++c) {
            a0[c] = make_float2(0.f, 0.f); a1[c] = make_float2(0.f, 0.f);
            a2[c] = make_float2(0.f, 0.f); a3[c] = make_float2(0.f, 0.f);
        }
        for (int base = lo; base < hi; base += 16) {
            int cnt = hi - base; if (cnt > 16) cnt = 16;
            int4 md = edesc[base + (lane & 15)];
            unsigned xp[16];
#pragma unroll
            for (int u = 0; u < 16; ++u) {             // 16 independent gathers
                int jc = (u < cnt) ? u : 0;
                int s = (int)__builtin_amdgcn_readlane((unsigned)md.x, (unsigned)jc);
                xp[u] = *(const unsigned*)(X + (size_t)s * 128 + 2 * lane);
            }
#pragma unroll
            for (int u = 0; u < 16; ++u) {
                if (u < cnt) {                         // wave-uniform guard
                    int row = (int)__builtin_amdgcn_readlane((unsigned)md.z, (unsigned)u) - nbase;
                    int tt  = (int)__builtin_amdgcn_readlane((unsigned)md.y, (unsigned)u);
                    float w = __int_as_float(__builtin_amdgcn_readlane((unsigned)md.w, (unsigned)u));
                    float4 cc = Cs[tt];
                    float xv0 = b2f(xp[u] & 0xffffu), xv1 = b2f(xp[u] >> 16);
                    float w0 = w * cc.x, w1 = w * cc.y, w2 = w * cc.z, w3 = w * cc.w;
                    if      (row == 0) ACC(a0)
                    else if (row == 1) ACC(a1)
                    else if (row == 2) ACC(a2)
                    else               ACC(a3)
                }
            }
        }
        // write 4 rows x 4 chunks, bf16-packed, xor-swizzled 16B chunks
        const int sw16 = lane >> 2, wo = 2 * (lane & 3);
#pragma unroll
        for (int r = 0; r < 4; ++r) {
            int R = wid * 4 + r;
            unsigned bo = (unsigned)(R * 128 + ((sw16 ^ (R & 15)) << 3) + wo);
            float2* A = (r == 0) ? a0 : (r == 1) ? a1 : (r == 2) ? a2 : a3;
#pragma unroll
            for (int c = 0; c < 4; ++c)
                *(unsigned*)(Sacc + c * (NPB * 128) + bo) = packbf(A[c].x, A[c].y);
        }
    }

    // ---------------- phase B: MFMA, m=32 n=128 K=640, Bs in LDS ----------------
    const int quad = lane >> 4, lr = lane & 15;
    const int wr = wid & 1, wc = wid >> 1;             // 2 m-tiles x 4 n-slices

    // prefetch X fragments for kc=4 (hidden behind kc=0..3 compute)
    bf16x8 ax[4];
    {
        int grow = rbase + wr * 16 + lr;               // always < N (3125*32 exact)
#pragma unroll
        for (int ks = 0; ks < 4; ++ks)
            ax[ks] = *(const bf16x8*)(X + (size_t)grow * 128 + ks * 32 + quad * 8);
    }

    floatx4 acc[2];
    acc[0] = (floatx4)0.0f; acc[1] = (floatx4)0.0f;

#pragma unroll
    for (int kc = 0; kc < 5; ++kc) {
        __syncthreads();                               // Sacc ready / prev Bs consumed
#pragma unroll
        for (int i = 0; i < 4; ++i) {                  // stage B chunk: 128 rows x 16 chunks
            int idx = i * 512 + t;
            int row = idx >> 4, ch = idx & 15;
            uint4 w = *(const uint4*)(WT + (size_t)row * 640 + kc * 128 + ch * 8);
            *(uint4*)(Bs + row * 128 + ((ch ^ (row & 15)) << 3)) = w;
        }
        __syncthreads();
#pragma unroll
        for (int ks = 0; ks < 4; ++ks) {
            bf16x8 a, b0, b1;
            int R = wr * 16 + lr;
            if (kc < 4) {
                int ch = ((ks * 4 + quad) ^ (R & 15)) << 3;
                a = *(const bf16x8*)(Sacc + kc * (NPB * 128) + R * 128 + ch);
            } else {
                a = ax[ks];
            }
            int sch = ((ks * 4 + quad) ^ lr) << 3;
            b0 = *(const bf16x8*)(Bs + (wc * 32 + lr) * 128 + sch);
            b1 = *(const bf16x8*)(Bs + (wc * 32 + 16 + lr) * 128 + sch);
            acc[0] = __builtin_amdgcn_mfma_f32_16x16x32_bf16(a, b0, acc[0], 0, 0, 0);
            acc[1] = __builtin_amdgcn_mfma_f32_16x16x32_bf16(a, b1, acc[1], 0, 0, 0);
        }
    }

    // C/D layout: col=lane&15, row=quad*4+reg  [m89/m91-verified]
#pragma unroll
    for (int reg = 0; reg < 4; ++reg) {
        int R = wr * 16 + quad * 4 + reg;
        int grow = rbase + R;
#pragma unroll
        for (int nj = 0; nj < 2; ++nj) {
            int n = wc * 32 + nj * 16 + lr;
            float v = acc[nj][reg] + bias[n];
            if (do_relu) v = v > 0.0f ? v : 0.0f;
            out[(size_t)grow * 128 + n] = f2b(v);
        }
    }
}

// ---- DistMult score: 16 lanes per edge, bf16 gathers ---------------------
__global__ __launch_bounds__(256) void k_score(const unsigned short* __restrict__ xf,
                                               const int* __restrict__ src, const int* __restrict__ dst,
                                               const int* __restrict__ et,
                                               const unsigned short* __restrict__ relb,
                                               float* __restrict__ out, int E) {
    int g = threadIdx.x >> 4, li = threadIdx.x & 15;
    int e = blockIdx.x * 16 + g;
    if (e >= E) return;
    int s = src[e], d = dst[e], tt = et[e];
    uint4 au = *(const uint4*)(xf + (size_t)s * 128 + li * 8);
    uint4 bu = *(const uint4*)(xf + (size_t)d * 128 + li * 8);
    uint4 ru = *(const uint4*)(relb + (size_t)tt * 128 + li * 8);
    float v;
    v  = b2f(au.x & 0xffffu) * b2f(ru.x & 0xffffu) * b2f(bu.x & 0xffffu);
    v += b2f(au.x >> 16)     * b2f(ru.x >> 16)     * b2f(bu.x >> 16);
    v += b2f(au.y & 0xffffu) * b2f(ru.y & 0xffffu) * b2f(bu.y & 0xffffu);
    v += b2f(au.y >> 16)     * b2f(ru.y >> 16)     * b2f(bu.y >> 16);
    v += b2f(au.z & 0xffffu) * b2f(ru.z & 0xffffu) * b2f(bu.z & 0xffffu);
    v += b2f(au.z >> 16)     * b2f(ru.z >> 16)     * b2f(bu.z >> 16);
    v += b2f(au.w & 0xffffu) * b2f(ru.w & 0xffffu) * b2f(bu.w & 0xffffu);
    v += b2f(au.w >> 16)     * b2f(ru.w >> 16)     * b2f(bu.w >> 16);
    v += __shfl_xor(v, 8, 16);
    v += __shfl_xor(v, 4, 16);
    v += __shfl_xor(v, 2, 16);
    v += __shfl_xor(v, 1, 16);
    if (li == 0) out[e] = v;
}

extern "C" void kernel_launch(void* const* d_in, const int* in_sizes, int n_in,
                              void* d_out, int out_size, void* d_ws, size_t ws_size,
                              hipStream_t stream) {
    (void)in_sizes; (void)n_in; (void)out_size; (void)ws_size;
    const int* edge_index = (const int*)d_in[0];
    const int* edge_type  = (const int*)d_in[1];
    const float* ent    = (const float*)d_in[2];
    const float* entb   = (const float*)d_in[3];
    const float* bases1 = (const float*)d_in[4];
    const float* comp1  = (const float*)d_in[5];
    const float* root1  = (const float*)d_in[6];
    const float* bias1  = (const float*)d_in[7];
    const float* bases2 = (const float*)d_in[8];
    const float* comp2  = (const float*)d_in[9];
    const float* root2  = (const float*)d_in[10];
    const float* bias2  = (const float*)d_in[11];
    const float* rel    = (const float*)d_in[12];
    const int* src = edge_index;
    const int* dst = edge_index + NE;

    char* ws = (char*)d_ws;
    size_t off_b = 0;
    auto alloc = [&](size_t bytes) { void* p = ws + off_b; off_b = (off_b + bytes + 255) & ~(size_t)255; return p; };

    unsigned short* x1   = (unsigned short*)alloc((size_t)N_NODES * 128 * 2);  // 25.6 MB
    unsigned short* x2   = (unsigned short*)alloc((size_t)N_NODES * 128 * 2);  // 25.6 MB
    unsigned short* wt1  = (unsigned short*)alloc(128 * 640 * 2);
    unsigned short* wt2  = (unsigned short*)alloc(128 * 640 * 2);
    unsigned short* relb = (unsigned short*)alloc(RR * DIM * 2);
    int*   deg    = (int*)alloc((size_t)N_NODES * 4);
    int*   cursor = (int*)alloc((size_t)N_NODES * 4);
    int*   offv   = (int*)alloc((size_t)(N_NODES + 1) * 4);
    int*   bsum   = (int*)alloc(NBLK * 4);
    int*   boff   = (int*)alloc(NBLK * 4);
    int4*  edesc  = (int4*)alloc((size_t)(NE + 64) * 16);                      // 6.4 MB + pad

    float* out = (float*)d_out;

    hipMemsetAsync(deg, 0, (size_t)N_NODES * 4, stream);
    hipMemsetAsync(cursor, 0, (size_t)N_NODES * 4, stream);

    k_deg<<<(NE + 255) / 256, 256, 0, stream>>>(dst, deg, NE);
    k_scan_block<<<NBLK, 256, 0, stream>>>(deg, bsum);
    k_scan_top<<<1, 256, 0, stream>>>(bsum, boff);
    k_scan_down<<<NBLK, 256, 0, stream>>>(deg, boff, offv);
    k_scatter<<<(NE + 255) / 256, 256, 0, stream>>>(src, dst, edge_type, offv, cursor, edesc, NE);
    k_norm2<<<(NE + 255) / 256, 256, 0, stream>>>(offv, edesc, NE);
    k_pre<<<50371, 256, 0, stream>>>(ent, entb, bases1, root1, bases2, root2, rel,
                                     x1, wt1, wt2, relb, out);

    int fgrid = N_NODES / NPB;   // 3125 (exact)
    // layer 1: x1 -> x2 (relu)
    k_fused<<<fgrid, 512, 0, stream>>>(x1, edesc, offv, comp1, wt1, bias1, x2, 1);
    // layer 2: x2 -> x1 (no relu); x1 becomes xf
    k_fused<<<fgrid, 512, 0, stream>>>(x2, edesc, offv, comp2, wt2, bias2, x1, 0);
    // decode
    k_score<<<(NE + 15) / 16, 256, 0, stream>>>(x1, src, dst, edge_type, relb, out, NE);
}